// Round 24
// baseline (93.091 us; speedup 1.0000x reference)
//
#include <hip/hip_runtime.h>
#include <math.h>

namespace {

constexpr int B_ = 4, N_ = 4, C_ = 64, H_ = 128, W_ = 128;
constexpr int HW_ = H_ * W_;

// out[:, 4] = ref
__global__ __launch_bounds__(256) void copyref_kernel(const float* __restrict__ ref,
                                                      float* __restrict__ out) {
    int t = blockIdx.x * 256 + threadIdx.x;      // one float4 per thread
    int f = t * 4;
    int b = f / (C_ * HW_);
    int within = f - b * (C_ * HW_);
    float4 v = *reinterpret_cast<const float4*>(ref + (size_t)b * C_ * HW_ + within);
    *reinterpret_cast<float4*>(out + (size_t)(b * 5 + N_) * C_ * HW_ + within) = v;
}

// SINGLE-BARRIER PERSISTENT-LDS kernel.
// Block = 2 output rows (256 threads, 1 px/thread); the block's ENTIRE working
// set (4 staged rows x 128 px x all 64 channels, fp32 = 128 KiB) is staged once
// in Phase A (128 independent coalesced loads/thread, own-pixel norms
// accumulated in registers as the data flies by), then ONE __syncthreads, then
// Phase B (dots from LDS + inline ref stream), softmax, Phase C (aggregate from
// the SAME resident LDS -- pass-2 restaging is gone -- + inline mean streams +
// store). Zero barriers after the first: waves free-run across phases, so the
// CU overlaps one wave's global streams with another's LDS/VALU work.
// Windowed variants (r12-r20) were pinned at 67-83 us by 32 sync points.
// LDS total 130 KiB < 160 KiB/CU -> 1 block/CU, 8 waves (VGPR headroom 256).
__global__ __launch_bounds__(256) void localcorr_kernel(const float* __restrict__ nbrs,
                                                        const float* __restrict__ ref,
                                                        float* __restrict__ out) {
    __shared__ float s_own[C_][4][128];   // 128 KiB: [channel][staged row][x]
    __shared__ float s_nrm[4][128];       // 2 KiB: per-pixel sq-norms

    const int blk = blockIdx.x;          // 0..1023
    const int ypair = blk & 63;
    const int bi = blk >> 6;
    const int i = bi & 3;
    const int b = bi >> 2;
    const int t = (int)threadIdx.x;
    const int x = t & 127;
    const int ry = t >> 7;               // 0/1, wave-uniform
    const int y0 = ypair * 2;
    const int y = y0 + ry;

    // reflect-pad (np 'reflect', pad=1)
    const int xm = (x == 0) ? 1 : x - 1;
    const int xp = (x == W_ - 1) ? W_ - 2 : x + 1;
    const int gyA = (y0 == 0) ? 1 : y0 - 1;
    const int gyC = y0 + 1;
    const int gyD = (y0 + 2 == H_) ? H_ - 2 : y0 + 2;
    const int myRowA = (ry == 0) ? gyA : gyC;   // staged row 2ry
    const int myRowB = (ry == 0) ? y0 : gyD;    // staged row 2ry+1

    const float* __restrict__ nb = nbrs + (size_t)(b * N_ + i) * C_ * HW_;
    const float* __restrict__ rp = ref + (size_t)b * C_ * HW_;
    const int offA = myRowA * W_ + x;
    const int offB = myRowB * W_ + x;
    const int offR = y * W_ + x;

    // ---- Phase A: stage ALL channels, accumulate own norms in-flight ----
    float nA = 0.f, nB = 0.f;
#pragma unroll 8
    for (int c = 0; c < C_; ++c) {
        const float o0 = nb[(size_t)c * HW_ + offA];
        const float o1 = nb[(size_t)c * HW_ + offB];
        nA += o0 * o0;
        nB += o1 * o1;
        s_own[c][2 * ry + 0][x] = o0;
        s_own[c][2 * ry + 1][x] = o1;
    }
    s_nrm[2 * ry + 0][x] = nA;
    s_nrm[2 * ry + 1][x] = nB;
    __syncthreads();                     // the ONLY barrier

    // ---- Phase B: dots + ref2 (LDS windows + inline ref stream) ----
    float dot[9];
#pragma unroll
    for (int k = 0; k < 9; ++k) dot[k] = 0.f;
    float r2 = 0.f;
#pragma unroll 4
    for (int c = 0; c < C_; ++c) {
        const float rf = rp[(size_t)c * HW_ + offR];
        const float* sc = &s_own[c][0][0];
        const float w00 = sc[(ry + 0) * 128 + xm], w01 = sc[(ry + 0) * 128 + x], w02 = sc[(ry + 0) * 128 + xp];
        const float w10 = sc[(ry + 1) * 128 + xm], w11 = sc[(ry + 1) * 128 + x], w12 = sc[(ry + 1) * 128 + xp];
        const float w20 = sc[(ry + 2) * 128 + xm], w21 = sc[(ry + 2) * 128 + x], w22 = sc[(ry + 2) * 128 + xp];
        r2 += rf * rf;
        dot[0] += rf * w00; dot[1] += rf * w01; dot[2] += rf * w02;
        dot[3] += rf * w10; dot[4] += rf * w11; dot[5] += rf * w12;
        dot[6] += rf * w20; dot[7] += rf * w21; dot[8] += rf * w22;
    }

    // ---- softmax over 9 neighbors (norms from s_nrm, already visible) ----
    float nk[9];
    nk[0] = s_nrm[ry + 0][xm]; nk[1] = s_nrm[ry + 0][x]; nk[2] = s_nrm[ry + 0][xp];
    nk[3] = s_nrm[ry + 1][xm]; nk[4] = s_nrm[ry + 1][x]; nk[5] = s_nrm[ry + 1][xp];
    nk[6] = s_nrm[ry + 2][xm]; nk[7] = s_nrm[ry + 2][x]; nk[8] = s_nrm[ry + 2][xp];

    const float invr = rsqrtf(fmaxf(r2, 1e-24f));
    float inv[9], d[9];
#pragma unroll
    for (int k = 0; k < 9; ++k) {
        inv[k] = rsqrtf(fmaxf(nk[k], 1e-24f));
        d[k] = dot[k] * invr * inv[k];
    }
    float mx = d[0];
#pragma unroll
    for (int k = 1; k < 9; ++k) mx = fmaxf(mx, d[k]);
    float ssum = 0.f;
#pragma unroll
    for (int k = 0; k < 9; ++k) { d[k] = __expf(d[k] - mx); ssum += d[k]; }
    const float is = 1.f / ssum;
    float wtp[9];
#pragma unroll
    for (int k = 0; k < 9; ++k) wtp[k] = d[k] * is * inv[k];

    // ---- Phase C: aggregate from resident LDS + wdiff + store (no barriers) ----
    const float* __restrict__ pm0 = nbrs + (size_t)(b * N_ + ((i + 1) & 3)) * C_ * HW_;
    const float* __restrict__ pm1 = nbrs + (size_t)(b * N_ + ((i + 2) & 3)) * C_ * HW_;
    const float* __restrict__ pm2 = nbrs + (size_t)(b * N_ + ((i + 3) & 3)) * C_ * HW_;
    float* __restrict__ op = out + (size_t)(b * 5 + i) * C_ * HW_ + offR;

#pragma unroll 4
    for (int c = 0; c < C_; ++c) {
        const float q0 = pm0[(size_t)c * HW_ + offR];
        const float q1 = pm1[(size_t)c * HW_ + offR];
        const float q2 = pm2[(size_t)c * HW_ + offR];
        const float* sc = &s_own[c][0][0];
        const float w00 = sc[(ry + 0) * 128 + xm], w01 = sc[(ry + 0) * 128 + x], w02 = sc[(ry + 0) * 128 + xp];
        const float w10 = sc[(ry + 1) * 128 + xm], w11 = sc[(ry + 1) * 128 + x], w12 = sc[(ry + 1) * 128 + xp];
        const float w20 = sc[(ry + 2) * 128 + xm], w21 = sc[(ry + 2) * 128 + x], w22 = sc[(ry + 2) * 128 + xp];
        const float agg = wtp[0] * w00 + wtp[1] * w01 + wtp[2] * w02
                        + wtp[3] * w10 + wtp[4] * w11 + wtp[5] * w12
                        + wtp[6] * w20 + wtp[7] * w21 + wtp[8] * w22;
        const float ctr = w11;
        const float dd = ctr - 0.25f * (ctr + q0 + q1 + q2);
        op[(size_t)c * HW_] = agg * __expf(-dd * dd);
    }
}

}  // namespace

extern "C" void kernel_launch(void* const* d_in, const int* in_sizes, int n_in,
                              void* d_out, int out_size, void* d_ws, size_t ws_size,
                              hipStream_t stream) {
    const float* nbrs = (const float*)d_in[0];
    const float* ref = (const float*)d_in[1];
    float* out = (float*)d_out;

    // slot 4 = ref copy
    copyref_kernel<<<(B_ * C_ * HW_ / 4) / 256, 256, 0, stream>>>(ref, out);

    // main: B*N*(H/2) = 1024 two-row blocks of 256 threads, single barrier
    localcorr_kernel<<<B_ * N_ * (H_ / 2), 256, 0, stream>>>(nbrs, ref, out);
}

// Round 25
// 84.014 us; speedup vs baseline: 1.1080x; 1.1080x over previous
//
#include <hip/hip_runtime.h>
#include <math.h>

namespace {

constexpr int B_ = 4, N_ = 4, C_ = 64, H_ = 128, W_ = 128;
constexpr int HW_ = H_ * W_;

// out[:, 4] = ref
__global__ __launch_bounds__(256) void copyref_kernel(const float* __restrict__ ref,
                                                      float* __restrict__ out) {
    int t = blockIdx.x * 256 + threadIdx.x;      // one float4 per thread
    int f = t * 4;
    int b = f / (C_ * HW_);
    int within = f - b * (C_ * HW_);
    float4 v = *reinterpret_cast<const float4*>(ref + (size_t)b * C_ * HW_ + within);
    *reinterpret_cast<float4*>(out + (size_t)(b * 5 + N_) * C_ * HW_ + within) = v;
}

__device__ __forceinline__ unsigned short f2bf(float v) {      // RNE bf16 round
    unsigned u = __float_as_uint(v);
    u += 0x7FFFu + ((u >> 16) & 1u);
    return (unsigned short)(u >> 16);
}
__device__ __forceinline__ float bf2f(unsigned short s) {
    return __uint_as_float((unsigned)s << 16);
}

// SINGLE-BARRIER PERSISTENT-LDS, bf16 window store.
// r24 proved persistence cuts FETCH to 91 MB but fp32 LDS (130 KiB) forced
// 1 block/CU (8 waves) -> latency-bound at 108 us. bf16 halves s_own to
// 64 KiB (+2 KiB fp32 norms) -> 2 blocks/CU, 16 waves/CU = r14's TLP with
// r24's traffic. Norms stay fp32-exact (computed from in-flight values in
// Phase A). bf16 window error ~4e-3 rel -> absmax ~5e-3 vs 0.104 threshold.
// VGPR must stay <=128 for the 2-block gate: unrolls kept small (4/2/2).
__global__ __launch_bounds__(256) void localcorr_kernel(const float* __restrict__ nbrs,
                                                        const float* __restrict__ ref,
                                                        float* __restrict__ out) {
    __shared__ unsigned short s_own[C_][4][128];   // 64 KiB bf16 windows
    __shared__ float s_nrm[4][128];                // 2 KiB fp32 norms

    const int blk = blockIdx.x;          // 0..1023
    const int ypair = blk & 63;
    const int bi = blk >> 6;
    const int i = bi & 3;
    const int b = bi >> 2;
    const int t = (int)threadIdx.x;
    const int x = t & 127;
    const int ry = t >> 7;               // 0/1, wave-uniform
    const int y0 = ypair * 2;
    const int y = y0 + ry;

    // reflect-pad (np 'reflect', pad=1)
    const int xm = (x == 0) ? 1 : x - 1;
    const int xp = (x == W_ - 1) ? W_ - 2 : x + 1;
    const int gyA = (y0 == 0) ? 1 : y0 - 1;
    const int gyC = y0 + 1;
    const int gyD = (y0 + 2 == H_) ? H_ - 2 : y0 + 2;
    const int myRowA = (ry == 0) ? gyA : gyC;   // staged row 2ry
    const int myRowB = (ry == 0) ? y0 : gyD;    // staged row 2ry+1

    const float* __restrict__ nb = nbrs + (size_t)(b * N_ + i) * C_ * HW_;
    const float* __restrict__ rp = ref + (size_t)b * C_ * HW_;
    const int offA = myRowA * W_ + x;
    const int offB = myRowB * W_ + x;
    const int offR = y * W_ + x;

    // ---- Phase A: stage ALL channels (bf16), norms fp32 in-flight ----
    float nA = 0.f, nB = 0.f;
#pragma unroll 4
    for (int c = 0; c < C_; ++c) {
        const float o0 = nb[(size_t)c * HW_ + offA];
        const float o1 = nb[(size_t)c * HW_ + offB];
        nA += o0 * o0;
        nB += o1 * o1;
        s_own[c][2 * ry + 0][x] = f2bf(o0);
        s_own[c][2 * ry + 1][x] = f2bf(o1);
    }
    s_nrm[2 * ry + 0][x] = nA;
    s_nrm[2 * ry + 1][x] = nB;
    __syncthreads();                     // the ONLY barrier

    // ---- Phase B: dots + ref2 (bf16 LDS windows + inline ref stream) ----
    float dot[9];
#pragma unroll
    for (int k = 0; k < 9; ++k) dot[k] = 0.f;
    float r2 = 0.f;
#pragma unroll 2
    for (int c = 0; c < C_; ++c) {
        const float rf = rp[(size_t)c * HW_ + offR];
        const unsigned short* sc = &s_own[c][0][0];
        const float w00 = bf2f(sc[(ry + 0) * 128 + xm]), w01 = bf2f(sc[(ry + 0) * 128 + x]), w02 = bf2f(sc[(ry + 0) * 128 + xp]);
        const float w10 = bf2f(sc[(ry + 1) * 128 + xm]), w11 = bf2f(sc[(ry + 1) * 128 + x]), w12 = bf2f(sc[(ry + 1) * 128 + xp]);
        const float w20 = bf2f(sc[(ry + 2) * 128 + xm]), w21 = bf2f(sc[(ry + 2) * 128 + x]), w22 = bf2f(sc[(ry + 2) * 128 + xp]);
        r2 += rf * rf;
        dot[0] += rf * w00; dot[1] += rf * w01; dot[2] += rf * w02;
        dot[3] += rf * w10; dot[4] += rf * w11; dot[5] += rf * w12;
        dot[6] += rf * w20; dot[7] += rf * w21; dot[8] += rf * w22;
    }

    // ---- softmax over 9 neighbors (norms fp32 from s_nrm) ----
    float nk[9];
    nk[0] = s_nrm[ry + 0][xm]; nk[1] = s_nrm[ry + 0][x]; nk[2] = s_nrm[ry + 0][xp];
    nk[3] = s_nrm[ry + 1][xm]; nk[4] = s_nrm[ry + 1][x]; nk[5] = s_nrm[ry + 1][xp];
    nk[6] = s_nrm[ry + 2][xm]; nk[7] = s_nrm[ry + 2][x]; nk[8] = s_nrm[ry + 2][xp];

    const float invr = rsqrtf(fmaxf(r2, 1e-24f));
    float inv[9], d[9];
#pragma unroll
    for (int k = 0; k < 9; ++k) {
        inv[k] = rsqrtf(fmaxf(nk[k], 1e-24f));
        d[k] = dot[k] * invr * inv[k];
    }
    float mx = d[0];
#pragma unroll
    for (int k = 1; k < 9; ++k) mx = fmaxf(mx, d[k]);
    float ssum = 0.f;
#pragma unroll
    for (int k = 0; k < 9; ++k) { d[k] = __expf(d[k] - mx); ssum += d[k]; }
    const float is = 1.f / ssum;
    float wtp[9];
#pragma unroll
    for (int k = 0; k < 9; ++k) wtp[k] = d[k] * is * inv[k];

    // ---- Phase C: aggregate from resident bf16 LDS + wdiff + store ----
    const float* __restrict__ pm0 = nbrs + (size_t)(b * N_ + ((i + 1) & 3)) * C_ * HW_;
    const float* __restrict__ pm1 = nbrs + (size_t)(b * N_ + ((i + 2) & 3)) * C_ * HW_;
    const float* __restrict__ pm2 = nbrs + (size_t)(b * N_ + ((i + 3) & 3)) * C_ * HW_;
    float* __restrict__ op = out + (size_t)(b * 5 + i) * C_ * HW_ + offR;

#pragma unroll 2
    for (int c = 0; c < C_; ++c) {
        const float q0 = pm0[(size_t)c * HW_ + offR];
        const float q1 = pm1[(size_t)c * HW_ + offR];
        const float q2 = pm2[(size_t)c * HW_ + offR];
        const unsigned short* sc = &s_own[c][0][0];
        const float w00 = bf2f(sc[(ry + 0) * 128 + xm]), w01 = bf2f(sc[(ry + 0) * 128 + x]), w02 = bf2f(sc[(ry + 0) * 128 + xp]);
        const float w10 = bf2f(sc[(ry + 1) * 128 + xm]), w11 = bf2f(sc[(ry + 1) * 128 + x]), w12 = bf2f(sc[(ry + 1) * 128 + xp]);
        const float w20 = bf2f(sc[(ry + 2) * 128 + xm]), w21 = bf2f(sc[(ry + 2) * 128 + x]), w22 = bf2f(sc[(ry + 2) * 128 + xp]);
        const float agg = wtp[0] * w00 + wtp[1] * w01 + wtp[2] * w02
                        + wtp[3] * w10 + wtp[4] * w11 + wtp[5] * w12
                        + wtp[6] * w20 + wtp[7] * w21 + wtp[8] * w22;
        const float ctr = w11;
        const float dd = ctr - 0.25f * (ctr + q0 + q1 + q2);
        op[(size_t)c * HW_] = agg * __expf(-dd * dd);
    }
}

}  // namespace

extern "C" void kernel_launch(void* const* d_in, const int* in_sizes, int n_in,
                              void* d_out, int out_size, void* d_ws, size_t ws_size,
                              hipStream_t stream) {
    const float* nbrs = (const float*)d_in[0];
    const float* ref = (const float*)d_in[1];
    float* out = (float*)d_out;

    // slot 4 = ref copy
    copyref_kernel<<<(B_ * C_ * HW_ / 4) / 256, 256, 0, stream>>>(ref, out);

    // main: B*N*(H/2) = 1024 two-row blocks of 256 threads, single barrier
    localcorr_kernel<<<B_ * N_ * (H_ / 2), 256, 0, stream>>>(nbrs, ref, out);
}

// Round 26
// 80.897 us; speedup vs baseline: 1.1507x; 1.0385x over previous
//
#include <hip/hip_runtime.h>
#include <math.h>

namespace {

constexpr int B_ = 4, N_ = 4, C_ = 64, H_ = 128, W_ = 128;
constexpr int HW_ = H_ * W_;
constexpr int CPB = 8;               // channels per barrier window
constexpr int NWIN = C_ / CPB;       // 8 windows per pass

// out[:, 4] = ref
__global__ __launch_bounds__(256) void copyref_kernel(const float* __restrict__ ref,
                                                      float* __restrict__ out) {
    int t = blockIdx.x * 256 + threadIdx.x;      // one float4 per thread
    int f = t * 4;
    int b = f / (C_ * HW_);
    int within = f - b * (C_ * HW_);
    float4 v = *reinterpret_cast<const float4*>(ref + (size_t)b * C_ * HW_ + within);
    *reinterpret_cast<float4*>(out + (size_t)(b * 5 + N_) * C_ * HW_ + within) = v;
}

__device__ __forceinline__ unsigned short f2bf(float v) {      // RNE bf16 round
    unsigned u = __float_as_uint(v);
    u += 0x7FFFu + ((u >> 16) & 1u);
    return (unsigned short)(u >> 16);
}
__device__ __forceinline__ float bf2f(unsigned short s) {
    return __uint_as_float((unsigned)s << 16);
}

// Windowed staging with bf16 LDS slots: CPB=8 at r14's 18 KB footprint.
// 1 px/thread, 2 rows/block (256 threads), grid = 1024 -> 4 blocks/CU =
// 16 waves/CU (max TLP at 1px/thread) AND 8-deep windows (16 barriers vs
// r14's 32, 2x in-flight loads per window). r20 proved CPB=8 fails at fp32
// (34 KB LDS -> 2 blocks/CU); r25 proved bf16 windows pass numerics
// (absmax 9.8e-4 vs 0.104). Norms stay fp32-exact from in-flight values.
__global__ __launch_bounds__(256) void localcorr_kernel(const float* __restrict__ nbrs,
                                                        const float* __restrict__ ref,
                                                        float* __restrict__ out) {
    __shared__ unsigned short s_own[2 * CPB][4][128];  // 16 KB bf16 windows
    __shared__ float s_nrm[4][128];                    // 2 KB fp32 norms

    const int blk = blockIdx.x;          // 0..1023
    const int ypair = blk & 63;
    const int bi = blk >> 6;
    const int i = bi & 3;
    const int b = bi >> 2;
    const int t = (int)threadIdx.x;
    const int x = t & 127;
    const int ry = t >> 7;               // 0/1, wave-uniform
    const int y0 = ypair * 2;
    const int y = y0 + ry;

    // reflect-pad (np 'reflect', pad=1)
    const int xm = (x == 0) ? 1 : x - 1;
    const int xp = (x == W_ - 1) ? W_ - 2 : x + 1;
    const int gyA = (y0 == 0) ? 1 : y0 - 1;
    const int gyC = y0 + 1;
    const int gyD = (y0 + 2 == H_) ? H_ - 2 : y0 + 2;
    const int myRowA = (ry == 0) ? gyA : gyC;   // staged row 2ry
    const int myRowB = (ry == 0) ? y0 : gyD;    // staged row 2ry+1

    const float* __restrict__ nb = nbrs + (size_t)(b * N_ + i) * C_ * HW_;
    const float* __restrict__ rp = ref + (size_t)b * C_ * HW_;
    const int offA = myRowA * W_ + x;
    const int offB = myRowB * W_ + x;
    const int offR = y * W_ + x;

    float dot[9];
#pragma unroll
    for (int k = 0; k < 9; ++k) dot[k] = 0.f;
    float nA = 0.f, nB = 0.f, r2 = 0.f;

    // ---- pass 1: dots + norms + ref2 ----
    float co0[CPB], co1[CPB], crf[CPB];
    float no0[CPB], no1[CPB], nrf[CPB];
#pragma unroll
    for (int u = 0; u < CPB; ++u) {
        const size_t co = (size_t)u * HW_;
        co0[u] = nb[co + offA]; co1[u] = nb[co + offB]; crf[u] = rp[co + offR];
    }
#pragma unroll 1
    for (int w = 0; w < NWIN; ++w) {
        const int base = (w & 1) * CPB;
#pragma unroll
        for (int u = 0; u < CPB; ++u) {
            s_own[base + u][2 * ry + 0][x] = f2bf(co0[u]);
            s_own[base + u][2 * ry + 1][x] = f2bf(co1[u]);
        }
        if (w + 1 < NWIN) {
#pragma unroll
            for (int u = 0; u < CPB; ++u) {
                const size_t co = (size_t)((w + 1) * CPB + u) * HW_;
                no0[u] = nb[co + offA]; no1[u] = nb[co + offB]; nrf[u] = rp[co + offR];
            }
        }
        __syncthreads();
#pragma unroll
        for (int u = 0; u < CPB; ++u) {
            const unsigned short* sc = &s_own[base + u][0][0];
            const float w00 = bf2f(sc[(ry + 0) * 128 + xm]), w02 = bf2f(sc[(ry + 0) * 128 + xp]);
            const float w10 = bf2f(sc[(ry + 1) * 128 + xm]), w12 = bf2f(sc[(ry + 1) * 128 + xp]);
            const float w20 = bf2f(sc[(ry + 2) * 128 + xm]), w22 = bf2f(sc[(ry + 2) * 128 + xp]);
            float w01, w11, w21;
            if (ry == 0) { w01 = co0[u]; w11 = co1[u]; w21 = bf2f(sc[2 * 128 + x]); }
            else         { w01 = bf2f(sc[1 * 128 + x]); w11 = co0[u]; w21 = co1[u]; }
            const float rf = crf[u];
            nA += co0[u] * co0[u]; nB += co1[u] * co1[u]; r2 += rf * rf;
            dot[0] += rf * w00; dot[1] += rf * w01; dot[2] += rf * w02;
            dot[3] += rf * w10; dot[4] += rf * w11; dot[5] += rf * w12;
            dot[6] += rf * w20; dot[7] += rf * w21; dot[8] += rf * w22;
        }
#pragma unroll
        for (int u = 0; u < CPB; ++u) { co0[u] = no0[u]; co1[u] = no1[u]; crf[u] = nrf[u]; }
    }

    // ---- share norms (fp32), softmax in-register ----
    s_nrm[2 * ry + 0][x] = nA;
    s_nrm[2 * ry + 1][x] = nB;
    __syncthreads();
    float nk[9];
    nk[0] = s_nrm[ry + 0][xm]; nk[1] = s_nrm[ry + 0][x]; nk[2] = s_nrm[ry + 0][xp];
    nk[3] = s_nrm[ry + 1][xm]; nk[4] = s_nrm[ry + 1][x]; nk[5] = s_nrm[ry + 1][xp];
    nk[6] = s_nrm[ry + 2][xm]; nk[7] = s_nrm[ry + 2][x]; nk[8] = s_nrm[ry + 2][xp];

    const float invr = rsqrtf(fmaxf(r2, 1e-24f));
    float inv[9], d[9];
#pragma unroll
    for (int k = 0; k < 9; ++k) {
        inv[k] = rsqrtf(fmaxf(nk[k], 1e-24f));
        d[k] = dot[k] * invr * inv[k];
    }
    float mx = d[0];
#pragma unroll
    for (int k = 1; k < 9; ++k) mx = fmaxf(mx, d[k]);
    float ssum = 0.f;
#pragma unroll
    for (int k = 0; k < 9; ++k) { d[k] = __expf(d[k] - mx); ssum += d[k]; }
    const float is = 1.f / ssum;
    float wtp[9];
#pragma unroll
    for (int k = 0; k < 9; ++k) wtp[k] = d[k] * is * inv[k];

    // ---- pass 2: aggregate + wdiff + store ----
    const float* __restrict__ pm0 = nbrs + (size_t)(b * N_ + ((i + 1) & 3)) * C_ * HW_;
    const float* __restrict__ pm1 = nbrs + (size_t)(b * N_ + ((i + 2) & 3)) * C_ * HW_;
    const float* __restrict__ pm2 = nbrs + (size_t)(b * N_ + ((i + 3) & 3)) * C_ * HW_;
    float* __restrict__ op = out + (size_t)(b * 5 + i) * C_ * HW_ + offR;

    float q0c[CPB], q1c[CPB], q2c[CPB];
    float q0n[CPB], q1n[CPB], q2n[CPB];
#pragma unroll
    for (int u = 0; u < CPB; ++u) {
        const size_t co = (size_t)u * HW_;
        co0[u] = nb[co + offA]; co1[u] = nb[co + offB];
        q0c[u] = pm0[co + offR]; q1c[u] = pm1[co + offR]; q2c[u] = pm2[co + offR];
    }
#pragma unroll 1
    for (int w = 0; w < NWIN; ++w) {
        const int base = (w & 1) * CPB;
#pragma unroll
        for (int u = 0; u < CPB; ++u) {
            s_own[base + u][2 * ry + 0][x] = f2bf(co0[u]);
            s_own[base + u][2 * ry + 1][x] = f2bf(co1[u]);
        }
        if (w + 1 < NWIN) {
#pragma unroll
            for (int u = 0; u < CPB; ++u) {
                const size_t co = (size_t)((w + 1) * CPB + u) * HW_;
                no0[u] = nb[co + offA]; no1[u] = nb[co + offB];
                q0n[u] = pm0[co + offR]; q1n[u] = pm1[co + offR]; q2n[u] = pm2[co + offR];
            }
        }
        __syncthreads();
#pragma unroll
        for (int u = 0; u < CPB; ++u) {
            const unsigned short* sc = &s_own[base + u][0][0];
            const float w00 = bf2f(sc[(ry + 0) * 128 + xm]), w02 = bf2f(sc[(ry + 0) * 128 + xp]);
            const float w10 = bf2f(sc[(ry + 1) * 128 + xm]), w12 = bf2f(sc[(ry + 1) * 128 + xp]);
            const float w20 = bf2f(sc[(ry + 2) * 128 + xm]), w22 = bf2f(sc[(ry + 2) * 128 + xp]);
            float w01, w11, w21;
            if (ry == 0) { w01 = co0[u]; w11 = co1[u]; w21 = bf2f(sc[2 * 128 + x]); }
            else         { w01 = bf2f(sc[1 * 128 + x]); w11 = co0[u]; w21 = co1[u]; }
            const float agg = wtp[0] * w00 + wtp[1] * w01 + wtp[2] * w02
                            + wtp[3] * w10 + wtp[4] * w11 + wtp[5] * w12
                            + wtp[6] * w20 + wtp[7] * w21 + wtp[8] * w22;
            const float ctr = w11;
            const float dd = ctr - 0.25f * (ctr + q0c[u] + q1c[u] + q2c[u]);
            op[(size_t)(w * CPB + u) * HW_] = agg * __expf(-dd * dd);
        }
#pragma unroll
        for (int u = 0; u < CPB; ++u) {
            co0[u] = no0[u]; co1[u] = no1[u];
            q0c[u] = q0n[u]; q1c[u] = q1n[u]; q2c[u] = q2n[u];
        }
    }
}

}  // namespace

extern "C" void kernel_launch(void* const* d_in, const int* in_sizes, int n_in,
                              void* d_out, int out_size, void* d_ws, size_t ws_size,
                              hipStream_t stream) {
    const float* nbrs = (const float*)d_in[0];
    const float* ref = (const float*)d_in[1];
    float* out = (float*)d_out;

    // slot 4 = ref copy
    copyref_kernel<<<(B_ * C_ * HW_ / 4) / 256, 256, 0, stream>>>(ref, out);

    // main: B*N*(H/2) = 1024 two-row blocks of 256 threads
    localcorr_kernel<<<B_ * N_ * (H_ / 2), 256, 0, stream>>>(nbrs, ref, out);
}